// Round 6
// baseline (724.659 us; speedup 1.0000x reference)
//
#include <hip/hip_runtime.h>
#include <hip/hip_bf16.h>
#include <cstdint>
#include <math.h>

// ---------------------------------------------------------------------------
// MemTransformerLM (Transformer-XL layer) on MI355X / gfx950.
// Round 12: GEMM gets T4 counted-vmcnt across the barrier:
//  - 3-deep LDS buffers (48 KB, 3 blocks/CU), stage(t+2) issued in iter t,
//    barrier = "s_waitcnt vmcnt(4); s_barrier" (never drains the newest 4
//    in-flight loads). Epilogue iters use vmcnt(0). This removes the
//    per-iteration staging-latency drain that __syncthreads (vmcnt 0) forced
//    — the m233/m218 2-phase stall.
//  - flash/LN/convert/transpose unchanged (flash is the control: expect
//    identical counters).
// ---------------------------------------------------------------------------

using bf16 = __hip_bfloat16;
using bf16x8 = __attribute__((ext_vector_type(8))) __bf16;
using f32x4  = __attribute__((ext_vector_type(4))) float;

__device__ __forceinline__ float b2f(unsigned u) {
  union { unsigned u; float f; } x; x.u = u << 16; return x.f;
}
__device__ __forceinline__ unsigned f2b_u(float f) {
  bf16 h = __float2bfloat16(f);
  return (unsigned)__builtin_bit_cast(unsigned short, h);
}

__device__ __forceinline__ float waveReduceSum(float x) {
  #pragma unroll
  for (int o = 32; o > 0; o >>= 1) x += __shfl_down(x, o, 64);
  return x;
}

// DPP move within 16-lane rows (VALU pipe — keeps LDS pipe free)
template<int CTRL>
__device__ __forceinline__ float dppMovF(float x) {
  return __builtin_bit_cast(float,
      __builtin_amdgcn_mov_dpp(__builtin_bit_cast(int, x), CTRL, 0xf, 0xf, true));
}
// reduce across the 16 lanes of each row via row_ror 1,2,4,8 (rotation tree)
__device__ __forceinline__ float rowMax16(float x) {
  x = fmaxf(x, dppMovF<0x121>(x));
  x = fmaxf(x, dppMovF<0x122>(x));
  x = fmaxf(x, dppMovF<0x124>(x));
  x = fmaxf(x, dppMovF<0x128>(x));
  return x;
}
__device__ __forceinline__ float rowSum16(float x) {
  x += dppMovF<0x121>(x);
  x += dppMovF<0x122>(x);
  x += dppMovF<0x124>(x);
  x += dppMovF<0x128>(x);
  return x;
}

// add two bf16x8 (as uint4 bit-patterns) in f32, repack to bf16x8
__device__ __forceinline__ bf16x8 addpack(uint4 a, uint4 b) {
  union { uint4 u; unsigned short s[8]; } ua, ub;
  ua.u = a; ub.u = b;
  union { bf16x8 v; unsigned short s[8]; } r;
  #pragma unroll
  for (int i = 0; i < 8; ++i) r.s[i] = (unsigned short)f2b_u(b2f(ua.s[i]) + b2f(ub.s[i]));
  return r.v;
}

// ---------------------------------------------------------------------------
// dtype detect (fp32 vs bf16 inputs) — parallel version (256 thr x 4 elems).
// ---------------------------------------------------------------------------
__global__ __launch_bounds__(256)
void detect_kernel(const unsigned* __restrict__ wraw, int* __restrict__ flag) {
  const int tid = threadIdx.x;
  int v = 0;
  #pragma unroll
  for (int u = 0; u < 4; ++u) {
    unsigned e = (wraw[tid * 4 + u] >> 7) & 0xffu;
    v += (e >= 0x5Au && e <= 0x8Au) ? 1 : 0;
  }
  #pragma unroll
  for (int o = 32; o > 0; o >>= 1) v += __shfl_down(v, o, 64);
  __shared__ int acc[4];
  if ((tid & 63) == 0) acc[tid >> 6] = v;
  __syncthreads();
  if (tid == 0) *flag = (acc[0] + acc[1] + acc[2] + acc[3] < 512) ? 1 : 0;
}

struct CvtTab {
  const void* src[22];
  bf16*       dst[22];
  int         n[22];
};

// seg 0 (= w) is written PERMUTED to batch-major "wb" layout:
// src element e = (i*4+b)*1024 + d  ->  dst (b*2048+i)*1024 + d
__global__ __launch_bounds__(256)
void convert_kernel(CvtTab tab, const int* __restrict__ flag) {
  const int seg = blockIdx.y;
  const int n   = tab.n[seg];
  const int f   = *flag;
  unsigned short* dst = (unsigned short*)tab.dst[seg];
  const int stride = gridDim.x * blockDim.x;
  for (int i = blockIdx.x * blockDim.x + threadIdx.x; i < n; i += stride) {
    float val;
    if (f) val = ((const float*)tab.src[seg])[i];
    else   val = b2f(((const unsigned short*)tab.src[seg])[i]);
    int di = i;
    if (seg == 0) {
      int ii = i >> 12, bb = (i >> 10) & 3, dd = i & 1023;
      di = (bb << 21) | (ii << 10) | dd;
    }
    dst[di] = (unsigned short)f2b_u(val);
  }
}

// ---------------------------------------------------------------------------
// Generic bf16 GEMM: C[M,N] = A[M,K] @ B[N,K]^T + bias, optional ReLU.
// 128x128 tile, BK=32, 4 waves (2x2). Round 12: 3-deep LDS pipeline with
// counted vmcnt across a raw s_barrier:
//   iter t: {waitcnt vmcnt(4); s_barrier}  -> stage(t) visible block-wide,
//           stage(t+1)'s 4 loads stay in flight (never drained);
//           issue stage(t+2); ds_read buf[t%3]; MFMA.
// Buffer overwrite safety: buf[(t+2)%3] last read in iter t-1, protected by
// iter-t barrier. t/nk wave-uniform -> barriers non-divergent.
// ---------------------------------------------------------------------------
template<bool RELU>
__global__ __launch_bounds__(256, 2)
void gemm_bt_kernel(const bf16* __restrict__ A, const bf16* __restrict__ B,
                    const bf16* __restrict__ bias, bf16* __restrict__ C,
                    int M, int N, int K) {
  __shared__ short As[3][128 * 32];
  __shared__ short Bs[3][128 * 32];

  const int tid  = threadIdx.x;
  const int lane = tid & 63;
  const int wv   = tid >> 6;
  const int row0 = blockIdx.y * 128;
  const int col0 = blockIdx.x * 128;

  const int wm = (wv & 1) * 64;
  const int wn = (wv >> 1) * 64;
  const int lm = lane & 15;
  const int kq = lane >> 4;

  const int st_r = lane >> 2;        // staging: lane -> row seg*16 + l/4
  const int st_c = (lane & 3) * 8;   //          col (l%4)*8 elements (16 B)

  auto stage = [&](int buf, int k0) {
    #pragma unroll
    for (int cc = 0; cc < 2; ++cc) {
      const int seg = wv * 2 + cc;
      const int r   = seg * 16 + st_r;
      const bf16* ga = A + (size_t)(row0 + r) * K + k0 + st_c;
      const bf16* gb = B + (size_t)(col0 + r) * K + k0 + st_c;
      __builtin_amdgcn_global_load_lds(
          (const __attribute__((address_space(1))) void*)ga,
          (__attribute__((address_space(3))) void*)(&As[buf][seg * 512]), 16, 0, 0);
      __builtin_amdgcn_global_load_lds(
          (const __attribute__((address_space(1))) void*)gb,
          (__attribute__((address_space(3))) void*)(&Bs[buf][seg * 512]), 16, 0, 0);
    }
  };

  f32x4 acc[4][4] = {};
  const int nk = K >> 5;             // >= 32 for all our shapes

  stage(0, 0);
  stage(1, 32);

  int cur = 0;
  for (int t = 0; t < nk; ++t) {
    // stage(t) must be complete; stage(t+1)'s 4 loads may stay in flight.
    if (t + 1 < nk) {
      asm volatile("s_waitcnt vmcnt(4)\n\ts_barrier" ::: "memory");
    } else {
      asm volatile("s_waitcnt vmcnt(0)\n\ts_barrier" ::: "memory");
    }
    if (t + 2 < nk) {
      const int nb = cur + 2 >= 3 ? cur - 1 : cur + 2;
      stage(nb, (t + 2) * 32);
    }

    bf16x8 af[4], bfr[4];
    #pragma unroll
    for (int tt = 0; tt < 4; ++tt) {
      af[tt]  = *(const bf16x8*)(const void*)(&As[cur][(wm + tt * 16 + lm) * 32 + kq * 8]);
      bfr[tt] = *(const bf16x8*)(const void*)(&Bs[cur][(wn + tt * 16 + lm) * 32 + kq * 8]);
    }
    #pragma unroll
    for (int mt = 0; mt < 4; ++mt)
      #pragma unroll
      for (int nt = 0; nt < 4; ++nt)
        acc[mt][nt] = __builtin_amdgcn_mfma_f32_16x16x32_bf16(
            af[mt], bfr[nt], acc[mt][nt], 0, 0, 0);

    cur = cur == 2 ? 0 : cur + 1;
  }
  // NOTE: no trailing barrier needed; each wave's last ds_reads are consumed
  // by its own MFMAs (lgkmcnt), and no further LDS writes occur.

  const unsigned short* bias_us = (const unsigned short*)bias;
  #pragma unroll
  for (int nt = 0; nt < 4; ++nt) {
    const int col = col0 + wn + nt * 16 + lm;
    const float bvc = b2f(bias_us[col]);
    #pragma unroll
    for (int mt = 0; mt < 4; ++mt) {
      #pragma unroll
      for (int rg = 0; rg < 4; ++rg) {
        const int row = row0 + wm + mt * 16 + kq * 4 + rg;
        float val = acc[mt][nt][rg] + bvc;
        if (RELU) val = fmaxf(val, 0.0f);
        C[(size_t)row * N + col] = __float2bfloat16(val);
      }
    }
  }
}

// ---------------------------------------------------------------------------
// V transpose: vT[n*64+d][b*2048+j] = qkv[b*2048+j][2048 + n*64+d]
// 64x64 tiles via padded LDS. grid (128, 16), 256 threads.
// ---------------------------------------------------------------------------
__global__ __launch_bounds__(256)
void transpose_v_kernel(const bf16* __restrict__ qkv, bf16* __restrict__ vT) {
  __shared__ short t[64][72];
  const int bjt = blockIdx.x;   // bj tile (0..127)
  const int ht  = blockIdx.y;   // h  tile (0..15)
  const int tid = threadIdx.x;
  #pragma unroll
  for (int u = 0; u < 2; ++u) {
    const int idx = tid + u * 256;       // 0..511
    const int row = idx >> 3;            // bj local 0..63
    const int c8  = (idx & 7) * 8;       // h local
    uint4 val = *(const uint4*)((const unsigned short*)qkv
                 + (size_t)(bjt * 64 + row) * 3072 + 2048 + ht * 64 + c8);
    *(uint4*)&t[row][c8] = val;
  }
  __syncthreads();
  #pragma unroll
  for (int u = 0; u < 2; ++u) {
    const int idx = tid + u * 256;
    const int hr  = idx >> 3;            // h local 0..63
    const int c8  = (idx & 7) * 8;       // bj local
    union { uint4 v; unsigned short s[8]; } o;
    #pragma unroll
    for (int e = 0; e < 8; ++e) o.s[e] = (unsigned short)t[c8 + e][hr];
    *(uint4*)((unsigned short*)vT + (size_t)(ht * 64 + hr) * 8192 + bjt * 64 + c8) = o.v;
  }
}

// ---------------------------------------------------------------------------
// Flash attention with banded rel-pos scores. One block = 128 Q-rows of one
// (b,n); 8 waves, each owning 16 Q-rows. Iterates causal j-tiles of 64.
// S = 0.125*(Qw·K^T + shuffle-gather(Qr·RKband^T)); online softmax; O += P·V.
// K/V/RK staged via global_load_lds width-16 into XOR-swizzled LDS; DPP row
// reduces; wave-uniform skip of fully-masked compute (last tile, waves 0-3).
// q,k come from merged qkv [b*2048+i][3072] (q cols 0.., k cols 1024..).
// Layouts: vT [n*64+d][b*2048+j]; rk [m][n*64+d]; av out [b*2048+i][n*64+d].
// ---------------------------------------------------------------------------
__global__ __launch_bounds__(512, 4)
void flash_attn_kernel(const bf16* __restrict__ qkv,
                       const bf16* __restrict__ vT, const bf16* __restrict__ rk,
                       const bf16* __restrict__ rwb, const bf16* __restrict__ rrb,
                       bf16* __restrict__ av) {
  const int bx = blockIdx.x;
  const int bn = bx & 63;
  const int p  = 15 - (bx >> 6);      // heavy chunks dispatched first
  const int b  = bn >> 4, n = bn & 15;
  const int i0 = p * 128;
  const int tid = threadIdx.x, lane = tid & 63, wv = tid >> 6;  // wv 0..7
  const int quad = lane >> 4, c = lane & 15;

  __shared__ short Ks[64 * 64];        //  8192 B  K tile  [j][d]  (swizzled)
  __shared__ short VTs[64 * 64];       //  8192 B  V^T tile [d][j] (swizzled)
  __shared__ short RKs[192 * 64];      // 24576 B  rk band  [m][d] (swizzled)
  __shared__ short Ps[8][16 * 72];     // 18432 B  per-wave P (A-frag layout)

  // staging lane geometry: 8 rows x 8 col-segments of 16B per wave-instr;
  // global source col pre-swizzled so linear LDS dest = XOR-swizzled tile
  const int srow = lane >> 3;                    // 0..7
  const int scol = ((lane & 7) ^ srow) * 8;      // shorts (16B units)
  // fragment-read swizzle (shorts): byte ^= (row&7)<<4
  const int rsw = (c & 7) << 3;

  // Q fragments (registers), biases pre-added
  bf16x8 qwf[2], qrf[2];
  {
    const unsigned short* qp  = (const unsigned short*)qkv +
        ((size_t)(b * 2048 + i0 + wv * 16 + c)) * 3072 + n * 64;
    const unsigned short* wbp = (const unsigned short*)rwb + n * 64;
    const unsigned short* rbp = (const unsigned short*)rrb + n * 64;
    #pragma unroll
    for (int ch = 0; ch < 2; ++ch) {
      const int off = ch * 32 + quad * 8;
      uint4 tq = *(const uint4*)(qp + off);
      uint4 tw = *(const uint4*)(wbp + off);
      uint4 tr = *(const uint4*)(rbp + off);
      qwf[ch] = addpack(tq, tw);
      qrf[ch] = addpack(tq, tr);
    }
  }

  f32x4 O[4] = {};
  float m_i[4] = {-INFINITY, -INFINITY, -INFINITY, -INFINITY};
  float l_i[4] = {0.f, 0.f, 0.f, 0.f};

  const unsigned short* kbase  = (const unsigned short*)qkv + ((size_t)b * 2048) * 3072 + 1024 + n * 64;
  const unsigned short* vbase  = (const unsigned short*)vT + ((size_t)(n * 64)) * 8192 + b * 2048;
  const unsigned short* rkbase = (const unsigned short*)rk + n * 64;
  const int gbase = 112 - wv * 16;    // per-wave band window base (0..112)
  short* pw = &Ps[wv][0];

  const int ntiles = 2 * p + 2;       // j-tiles: 0 .. 2p+1
  for (int jt = 0; jt < ntiles; ++jt) {
    const int j0 = jt * 64;
    const int cb = 1920 + j0 - i0;     // band start row (>= 0 always)

    // --- async stage K, V, RK direct to LDS (shared by all 8 waves) ---
    {
      const int row = wv * 8 + srow;
      const unsigned short* gk = kbase + (size_t)(j0 + row) * 3072 + scol;
      __builtin_amdgcn_global_load_lds(
          (const __attribute__((address_space(1))) void*)gk,
          (__attribute__((address_space(3))) void*)(Ks + wv * 512), 16, 0, 0);
      const unsigned short* gv = vbase + (size_t)row * 8192 + j0 + scol;
      __builtin_amdgcn_global_load_lds(
          (const __attribute__((address_space(1))) void*)gv,
          (__attribute__((address_space(3))) void*)(VTs + wv * 512), 16, 0, 0);
    }
    #pragma unroll
    for (int u = 0; u < 3; ++u) {
      const int seg = wv * 3 + u;          // 0..23
      const int row = seg * 8 + srow;      // 0..191
      int rr = cb + row; rr = rr < 2047 ? rr : 2047;  // clamp: masked-only
      const unsigned short* gr = rkbase + (size_t)rr * 1024 + scol;
      __builtin_amdgcn_global_load_lds(
          (const __attribute__((address_space(1))) void*)gr,
          (__attribute__((address_space(3))) void*)(RKs + seg * 512), 16, 0, 0);
    }
    __syncthreads();   // drains vmcnt(0): staged tiles visible to all waves

    // wave-uniform skip: all 16 rows of this wave causally masked
    if (i0 + wv * 16 + 15 >= j0) {
      // --- AC = Qw @ K^T  (16x64 per wave) ---
      f32x4 S[4] = {};
      __builtin_amdgcn_s_setprio(1);
      #pragma unroll
      for (int ch = 0; ch < 2; ++ch) {
        #pragma unroll
        for (int t = 0; t < 4; ++t) {
          bf16x8 bk = *(const bf16x8*)(const void*)
              &Ks[(t * 16 + c) * 64 + ((ch * 32 + quad * 8) ^ rsw)];
          S[t] = __builtin_amdgcn_mfma_f32_16x16x32_bf16(qwf[ch], bk, S[t], 0, 0, 0);
        }
      }
      // --- G = Qr @ RKband^T, 80-wide per-wave window ---
      f32x4 G[5] = {};
      #pragma unroll
      for (int ch = 0; ch < 2; ++ch) {
        #pragma unroll
        for (int t = 0; t < 5; ++t) {
          bf16x8 br = *(const bf16x8*)(const void*)
              &RKs[(gbase + t * 16 + c) * 64 + ((ch * 32 + quad * 8) ^ rsw)];
          G[t] = __builtin_amdgcn_mfma_f32_16x16x32_bf16(qrf[ch], br, G[t], 0, 0, 0);
        }
      }
      __builtin_amdgcn_s_setprio(0);

      // --- band gather via in-quad shuffles + scale/mask + online softmax ---
      float alpha[4];
      #pragma unroll
      for (int rg = 0; rg < 4; ++rg) {
        const int r  = quad * 4 + rg;          // local row 0..15
        const int ig = i0 + wv * 16 + r;       // global i
        const int offset = c + 15 - r;         // 0..30
        const int srcl = quad * 16 + (offset & 15);
        float gs[5];
        #pragma unroll
        for (int tt = 0; tt < 5; ++tt) gs[tt] = __shfl(G[tt][rg], srcl, 64);
        float v[4];
        #pragma unroll
        for (int u = 0; u < 4; ++u) {
          const float bd = (offset < 16) ? gs[u] : gs[u + 1];
          float s = 0.125f * (S[u][rg] + bd);
          if (j0 + u * 16 + c > ig) s = -INFINITY;
          v[u] = s;
        }
        float rmax = rowMax16(fmaxf(fmaxf(v[0], v[1]), fmaxf(v[2], v[3])));
        const float mn = fmaxf(m_i[rg], rmax);
        alpha[rg] = __expf(m_i[rg] - mn);      // first iter: exp(-inf)=0
        float rs = 0.f;
        #pragma unroll
        for (int u = 0; u < 4; ++u) {
          float p2 = __expf(v[u] - mn);
          rs += p2;
          pw[r * 72 + u * 16 + c] = (short)f2b_u(p2);
        }
        rs = rowSum16(rs);
        l_i[rg] = l_i[rg] * alpha[rg] + rs;
        m_i[rg] = mn;
      }
      #pragma unroll
      for (int t = 0; t < 4; ++t)
        #pragma unroll
        for (int rg = 0; rg < 4; ++rg)
          O[t][rg] *= alpha[rg];

      // --- O += P @ V --- (P via per-wave LDS round-trip; in-wave ordered)
      __builtin_amdgcn_s_setprio(1);
      #pragma unroll
      for (int ch = 0; ch < 2; ++ch) {
        bf16x8 ap = *(const bf16x8*)(const void*)&Ps[wv][c * 72 + ch * 32 + quad * 8];
        #pragma unroll
        for (int t = 0; t < 4; ++t) {
          bf16x8 bv2 = *(const bf16x8*)(const void*)
              &VTs[(t * 16 + c) * 64 + ((ch * 32 + quad * 8) ^ rsw)];
          O[t] = __builtin_amdgcn_mfma_f32_16x16x32_bf16(ap, bv2, O[t], 0, 0, 0);
        }
      }
      __builtin_amdgcn_s_setprio(0);
    }
    __syncthreads();   // all waves done reading before next staging overwrites
  }

  // epilogue: av[b*2048+i][n*64+d] bf16
  unsigned short* avp = (unsigned short*)av;
  #pragma unroll
  for (int rg = 0; rg < 4; ++rg) {
    const float inv = 1.0f / l_i[rg];
    const int i = i0 + wv * 16 + quad * 4 + rg;
    const size_t base = ((size_t)(b * 2048 + i)) * 1024 + n * 64;
    #pragma unroll
    for (int t = 0; t < 4; ++t)
      avp[base + t * 16 + c] = (unsigned short)f2b_u(O[t][rg] * inv);
  }
}

// ---------------------------------------------------------------------------
// LayerNorm over last dim (1024): out = (x+y-mu)*rsqrt(var+eps)*g + b
// Rows are [b*2048+i] order. FINAL: permute out row to (i*4+b), fp32 when
// *flag (fp32 world) else bf16.
// ---------------------------------------------------------------------------
template<bool FINAL>
__global__ __launch_bounds__(256)
void ln_kernel(const bf16* __restrict__ x, const bf16* __restrict__ y,
               const bf16* __restrict__ g, const bf16* __restrict__ bb,
               bf16* __restrict__ o_bf, float* __restrict__ o_f32,
               const int* __restrict__ flag) {
  const size_t row = blockIdx.x;
  const int tid  = threadIdx.x;
  const int lane = tid & 63;
  const int wv   = tid >> 6;

  const uint2 ux = ((const uint2*)((const unsigned short*)x + row * 1024))[tid];
  const uint2 uy = ((const uint2*)((const unsigned short*)y + row * 1024))[tid];
  float f[4];
  f[0] = b2f(ux.x & 0xffffu) + b2f(uy.x & 0xffffu);
  f[1] = b2f(ux.x >> 16)     + b2f(uy.x >> 16);
  f[2] = b2f(ux.y & 0xffffu) + b2f(uy.y & 0xffffu);
  f[3] = b2f(ux.y >> 16)     + b2f(uy.y >> 16);

  float s  = f[0] + f[1] + f[2] + f[3];
  float s2 = f[0]*f[0] + f[1]*f[1] + f[2]*f[2] + f[3]*f[3];
  s  = waveReduceSum(s);
  s2 = waveReduceSum(s2);
  __shared__ float r1[4], r2[4];
  if (lane == 0) { r1[wv] = s; r2[wv] = s2; }
  __syncthreads();
  s  = r1[0] + r1[1] + r1[2] + r1[3];
  s2 = r2[0] + r2[1] + r2[2] + r2[3];
  const float mu   = s * (1.0f / 1024.0f);
  const float var  = s2 * (1.0f / 1024.0f) - mu * mu;
  const float rstd = rsqrtf(var + 1e-5f);

  const uint2 ug = ((const uint2*)(const void*)g)[tid];
  const uint2 ub = ((const uint2*)(const void*)bb)[tid];
  float gv[4] = { b2f(ug.x & 0xffffu), b2f(ug.x >> 16), b2f(ug.y & 0xffffu), b2f(ug.y >> 16) };
  float bv[4] = { b2f(ub.x & 0xffffu), b2f(ub.x >> 16), b2f(ub.y & 0xffffu), b2f(ub.y >> 16) };

  float vout[4];
  #pragma unroll
  for (int c2 = 0; c2 < 4; ++c2)
    vout[c2] = (f[c2] - mu) * rstd * gv[c2] + bv[c2];

  size_t orow = row;
  if (FINAL) orow = (size_t)((row & 2047) * 4 + (row >> 11));  // [b][i] -> [i][b]

  if (FINAL && *flag) {
    float4 res = { vout[0], vout[1], vout[2], vout[3] };
    ((float4*)(o_f32 + orow * 1024))[tid] = res;
  } else {
    uint2 res;
    res.x = f2b_u(vout[0]) | (f2b_u(vout[1]) << 16);
    res.y = f2b_u(vout[2]) | (f2b_u(vout[3]) << 16);
    ((uint2*)((unsigned short*)o_bf + orow * 1024))[tid] = res;
  }
}

// ---------------------------------------------------------------------------

extern "C" void kernel_launch(void* const* d_in, const int* in_sizes, int n_in,
                              void* d_out, int out_size, void* d_ws, size_t ws_size,
                              hipStream_t stream) {
  (void)in_sizes; (void)n_in; (void)out_size; (void)ws_size;

  char* ws = (char*)d_ws;
  const size_t MB = 1u << 20;
  const size_t KB = 1u << 10;

  // converted bf16 inputs [0, 48 MiB)
  bf16* wb_b = (bf16*)(ws + 0 * MB);    // w, PERMUTED to [b*2048+i][dm]
  bf16* r_b  = (bf16*)(ws + 16 * MB);
  bf16* Wq_b = (bf16*)(ws + 20 * MB);   // Wq/Wk/Wv contiguous -> merged WQKV
  bf16* Wk_b = (bf16*)(ws + 22 * MB);
  bf16* Wv_b = (bf16*)(ws + 24 * MB);
  bf16* Wr_b = (bf16*)(ws + 26 * MB);
  bf16* Wo_b = (bf16*)(ws + 28 * MB);
  bf16* W1_b = (bf16*)(ws + 30 * MB);
  bf16* W2_b = (bf16*)(ws + 38 * MB);
  char* smalls = ws + 46 * MB;
  // merged QKV bias (3072 contiguous bf16 = 6 KB) in slot 0
  bf16* bq_b  = (bf16*)(smalls + 0 * 2 * KB);
  bf16* bk_b  = (bf16*)(smalls + 1 * 2 * KB);
  bf16* bv_b  = (bf16*)(smalls + 2 * 2 * KB);
  bf16* br_b  = (bf16*)(smalls + 3 * 8 * KB);
  bf16* bo_b  = (bf16*)(smalls + 4 * 8 * KB);
  bf16* rwb_b = (bf16*)(smalls + 5 * 8 * KB);
  bf16* rrb_b = (bf16*)(smalls + 6 * 8 * KB);
  bf16* g1_b  = (bf16*)(smalls + 7 * 8 * KB);
  bf16* lb1_b = (bf16*)(smalls + 8 * 8 * KB);
  bf16* b1_b  = (bf16*)(smalls + 9 * 8 * KB);
  bf16* b2_b  = (bf16*)(smalls + 10 * 8 * KB);
  bf16* g2_b  = (bf16*)(smalls + 11 * 8 * KB);
  bf16* lb2_b = (bf16*)(smalls + 12 * 8 * KB);
  int*  flag  = (int*)(ws + 47 * MB);

  // pipeline buffers, reused (high-water 144 MiB)
  bf16* qkv_ws  = (bf16*)(ws + 48 * MB);   // [b*2048+i][3072] (q|k|v)
  bf16* vT_ws   = (bf16*)(ws + 96 * MB);   // [h][b*2048+j]
  bf16* rk_ws   = (bf16*)(ws + 112 * MB);  // [m][h]
  bf16* av_ws   = (bf16*)(ws + 116 * MB);  // [b*2048+i][h]
  bf16* ao_ws   = (bf16*)(ws + 48 * MB);   // reuse qkv (dead after flash)
  bf16* out1_ws = (bf16*)(ws + 64 * MB);   // reuse qkv tail
  bf16* ff1_ws  = (bf16*)(ws + 80 * MB);   // 64 MiB [80,144): vT/rk/av dead after Wo
  bf16* core_ws = (bf16*)(ws + 48 * MB);   // reuse ao (dead after LN1)

  detect_kernel<<<dim3(1), dim3(256), 0, stream>>>((const unsigned*)d_in[0], flag);

  CvtTab tab;
  const int  srcidx[22] = {0,1,3,5,7,9,11,17,19, 4,6,8,10,12,13,14,15,16,18,20,21,22};
  bf16*      dsts[22]   = {wb_b,r_b,Wq_b,Wk_b,Wv_b,Wr_b,Wo_b,W1_b,W2_b,
                           bq_b,bk_b,bv_b,br_b,bo_b,rwb_b,rrb_b,g1_b,lb1_b,b1_b,b2_b,g2_b,lb2_b};
  const int  ns[22]     = {8388608,2097152,1048576,1048576,1048576,1048576,1048576,4194304,4194304,
                           1024,1024,1024,1024,1024,1024,1024,1024,1024,4096,1024,1024,1024};
  for (int s = 0; s < 22; ++s) { tab.src[s] = d_in[srcidx[s]]; tab.dst[s] = dsts[s]; tab.n[s] = ns[s]; }
  convert_kernel<<<dim3(512, 22), dim3(256), 0, stream>>>(tab, flag);

  const dim3 blk(256);

  // merged QKV projection: C[8192][3072] = wb @ [Wq;Wk;Wv]^T + [bq;bk;bv]
  gemm_bt_kernel<false><<<dim3(24, 64), blk, 0, stream>>>(wb_b, Wq_b, bq_b, qkv_ws, 8192, 3072, 1024);
  // V transpose to vT[h][bj]
  transpose_v_kernel<<<dim3(128, 16), blk, 0, stream>>>(qkv_ws, vT_ws);
  // rel-pos projection
  gemm_bt_kernel<false><<<dim3(8, 16), blk, 0, stream>>>(r_b, Wr_b, br_b, rk_ws, 2048, 1024, 1024);

  // flash attention: 1024 blocks of 512 threads (128 Q-rows each)
  flash_attn_kernel<<<dim3(1024), dim3(512), 0, stream>>>(qkv_ws, vT_ws, rk_ws, rwb_b, rrb_b, av_ws);

  // output projection + LN1
  gemm_bt_kernel<false><<<dim3(8, 64), blk, 0, stream>>>(av_ws, Wo_b, bo_b, ao_ws, 8192, 1024, 1024);
  ln_kernel<false><<<dim3(8192), blk, 0, stream>>>(wb_b, ao_ws, g1_b, lb1_b, out1_ws, nullptr, flag);

  // FFN (single-shot) + final LN (permutes rows back to [i][b], fp32 out)
  gemm_bt_kernel<true ><<<dim3(32, 64), blk, 0, stream>>>(out1_ws, W1_b, b1_b, ff1_ws, 8192, 4096, 1024);
  gemm_bt_kernel<false><<<dim3(8, 64), blk, 0, stream>>>(ff1_ws, W2_b, b2_b, core_ws, 8192, 1024, 4096);
  ln_kernel<true><<<dim3(8192), blk, 0, stream>>>(out1_ws, core_ws, g2_b, lb2_b, (bf16*)d_out, (float*)d_out, flag);
}

// Round 7
// 714.895 us; speedup vs baseline: 1.0137x; 1.0137x over previous
//
#include <hip/hip_runtime.h>
#include <hip/hip_bf16.h>
#include <cstdint>
#include <math.h>

// ---------------------------------------------------------------------------
// MemTransformerLM (Transformer-XL layer) on MI355X / gfx950.
// Round 13:
//  - GEMM: revert to 2-buffer dbuf (R5 form, measured best) but
//    __launch_bounds__(256,3): 3 co-resident blocks/CU hide the per-iter
//    barrier drain (m97/m114 mechanism). LDS 32 KB, VGPR ~130 <= 168.
//  - flash: RK band ring buffer (256 rows, 32 KB). Consecutive tiles share
//    128/192 band rows; stage only the 64 NEW rows per tile (1 gload/wave,
//    was 3) and issue it right after barrier (a) — its target ring slots are
//    outside the current read window, so the load hides under the whole
//    tile compute. Staged bytes/block-tile 40->24 KB.
//  - counted-vmcnt 3-buf GEMM reverted (R6: null, matches 2-phase gate).
// ---------------------------------------------------------------------------

using bf16 = __hip_bfloat16;
using bf16x8 = __attribute__((ext_vector_type(8))) __bf16;
using f32x4  = __attribute__((ext_vector_type(4))) float;

__device__ __forceinline__ float b2f(unsigned u) {
  union { unsigned u; float f; } x; x.u = u << 16; return x.f;
}
__device__ __forceinline__ unsigned f2b_u(float f) {
  bf16 h = __float2bfloat16(f);
  return (unsigned)__builtin_bit_cast(unsigned short, h);
}

__device__ __forceinline__ float waveReduceSum(float x) {
  #pragma unroll
  for (int o = 32; o > 0; o >>= 1) x += __shfl_down(x, o, 64);
  return x;
}

// DPP move within 16-lane rows (VALU pipe — keeps LDS pipe free)
template<int CTRL>
__device__ __forceinline__ float dppMovF(float x) {
  return __builtin_bit_cast(float,
      __builtin_amdgcn_mov_dpp(__builtin_bit_cast(int, x), CTRL, 0xf, 0xf, true));
}
// reduce across the 16 lanes of each row via row_ror 1,2,4,8 (rotation tree)
__device__ __forceinline__ float rowMax16(float x) {
  x = fmaxf(x, dppMovF<0x121>(x));
  x = fmaxf(x, dppMovF<0x122>(x));
  x = fmaxf(x, dppMovF<0x124>(x));
  x = fmaxf(x, dppMovF<0x128>(x));
  return x;
}
__device__ __forceinline__ float rowSum16(float x) {
  x += dppMovF<0x121>(x);
  x += dppMovF<0x122>(x);
  x += dppMovF<0x124>(x);
  x += dppMovF<0x128>(x);
  return x;
}

// add two bf16x8 (as uint4 bit-patterns) in f32, repack to bf16x8
__device__ __forceinline__ bf16x8 addpack(uint4 a, uint4 b) {
  union { uint4 u; unsigned short s[8]; } ua, ub;
  ua.u = a; ub.u = b;
  union { bf16x8 v; unsigned short s[8]; } r;
  #pragma unroll
  for (int i = 0; i < 8; ++i) r.s[i] = (unsigned short)f2b_u(b2f(ua.s[i]) + b2f(ub.s[i]));
  return r.v;
}

// ---------------------------------------------------------------------------
// dtype detect (fp32 vs bf16 inputs) — parallel version (256 thr x 4 elems).
// ---------------------------------------------------------------------------
__global__ __launch_bounds__(256)
void detect_kernel(const unsigned* __restrict__ wraw, int* __restrict__ flag) {
  const int tid = threadIdx.x;
  int v = 0;
  #pragma unroll
  for (int u = 0; u < 4; ++u) {
    unsigned e = (wraw[tid * 4 + u] >> 7) & 0xffu;
    v += (e >= 0x5Au && e <= 0x8Au) ? 1 : 0;
  }
  #pragma unroll
  for (int o = 32; o > 0; o >>= 1) v += __shfl_down(v, o, 64);
  __shared__ int acc[4];
  if ((tid & 63) == 0) acc[tid >> 6] = v;
  __syncthreads();
  if (tid == 0) *flag = (acc[0] + acc[1] + acc[2] + acc[3] < 512) ? 1 : 0;
}

struct CvtTab {
  const void* src[22];
  bf16*       dst[22];
  int         n[22];
};

// seg 0 (= w) is written PERMUTED to batch-major "wb" layout:
// src element e = (i*4+b)*1024 + d  ->  dst (b*2048+i)*1024 + d
__global__ __launch_bounds__(256)
void convert_kernel(CvtTab tab, const int* __restrict__ flag) {
  const int seg = blockIdx.y;
  const int n   = tab.n[seg];
  const int f   = *flag;
  unsigned short* dst = (unsigned short*)tab.dst[seg];
  const int stride = gridDim.x * blockDim.x;
  for (int i = blockIdx.x * blockDim.x + threadIdx.x; i < n; i += stride) {
    float val;
    if (f) val = ((const float*)tab.src[seg])[i];
    else   val = b2f(((const unsigned short*)tab.src[seg])[i]);
    int di = i;
    if (seg == 0) {
      int ii = i >> 12, bb = (i >> 10) & 3, dd = i & 1023;
      di = (bb << 21) | (ii << 10) | dd;
    }
    dst[di] = (unsigned short)f2b_u(val);
  }
}

// ---------------------------------------------------------------------------
// Generic bf16 GEMM: C[M,N] = A[M,K] @ B[N,K]^T + bias, optional ReLU.
// 128x128 tile, BK=32, 4 waves (2x2). Double-buffered LDS (32 KB), ONE
// barrier per K-step; stage(t+1) issued before compute(t). launch_bounds
// (256,3): 3 blocks/CU co-resident hide the barrier drain (m97/m114).
// ---------------------------------------------------------------------------
template<bool RELU>
__global__ __launch_bounds__(256, 3)
void gemm_bt_kernel(const bf16* __restrict__ A, const bf16* __restrict__ B,
                    const bf16* __restrict__ bias, bf16* __restrict__ C,
                    int M, int N, int K) {
  __shared__ short As[2][128 * 32];
  __shared__ short Bs[2][128 * 32];

  const int tid  = threadIdx.x;
  const int lane = tid & 63;
  const int wv   = tid >> 6;
  const int row0 = blockIdx.y * 128;
  const int col0 = blockIdx.x * 128;

  const int wm = (wv & 1) * 64;
  const int wn = (wv >> 1) * 64;
  const int lm = lane & 15;
  const int kq = lane >> 4;

  const int st_r = lane >> 2;        // staging: lane -> row seg*16 + l/4
  const int st_c = (lane & 3) * 8;   //          col (l%4)*8 elements (16 B)

  auto stage = [&](int buf, int k0) {
    #pragma unroll
    for (int cc = 0; cc < 2; ++cc) {
      const int seg = wv * 2 + cc;
      const int r   = seg * 16 + st_r;
      const bf16* ga = A + (size_t)(row0 + r) * K + k0 + st_c;
      const bf16* gb = B + (size_t)(col0 + r) * K + k0 + st_c;
      __builtin_amdgcn_global_load_lds(
          (const __attribute__((address_space(1))) void*)ga,
          (__attribute__((address_space(3))) void*)(&As[buf][seg * 512]), 16, 0, 0);
      __builtin_amdgcn_global_load_lds(
          (const __attribute__((address_space(1))) void*)gb,
          (__attribute__((address_space(3))) void*)(&Bs[buf][seg * 512]), 16, 0, 0);
    }
  };

  f32x4 acc[4][4] = {};
  const int nk = K >> 5;

  stage(0, 0);
  __syncthreads();            // buf0 staged (vmcnt drained by barrier)

  int cur = 0;
  for (int t = 0; t < nk; ++t) {
    if (t + 1 < nk) stage(cur ^ 1, (t + 1) * 32);   // issue next: hides under compute

    bf16x8 af[4], bfr[4];
    #pragma unroll
    for (int tt = 0; tt < 4; ++tt) {
      af[tt]  = *(const bf16x8*)(const void*)(&As[cur][(wm + tt * 16 + lm) * 32 + kq * 8]);
      bfr[tt] = *(const bf16x8*)(const void*)(&Bs[cur][(wn + tt * 16 + lm) * 32 + kq * 8]);
    }
    #pragma unroll
    for (int mt = 0; mt < 4; ++mt)
      #pragma unroll
      for (int nt = 0; nt < 4; ++nt)
        acc[mt][nt] = __builtin_amdgcn_mfma_f32_16x16x32_bf16(
            af[mt], bfr[nt], acc[mt][nt], 0, 0, 0);

    __syncthreads();          // next staging complete + all reads of cur done
    cur ^= 1;
  }

  const unsigned short* bias_us = (const unsigned short*)bias;
  #pragma unroll
  for (int nt = 0; nt < 4; ++nt) {
    const int col = col0 + wn + nt * 16 + lm;
    const float bvc = b2f(bias_us[col]);
    #pragma unroll
    for (int mt = 0; mt < 4; ++mt) {
      #pragma unroll
      for (int rg = 0; rg < 4; ++rg) {
        const int row = row0 + wm + mt * 16 + kq * 4 + rg;
        float val = acc[mt][nt][rg] + bvc;
        if (RELU) val = fmaxf(val, 0.0f);
        C[(size_t)row * N + col] = __float2bfloat16(val);
      }
    }
  }
}

// ---------------------------------------------------------------------------
// V transpose: vT[n*64+d][b*2048+j] = qkv[b*2048+j][2048 + n*64+d]
// 64x64 tiles via padded LDS. grid (128, 16), 256 threads.
// ---------------------------------------------------------------------------
__global__ __launch_bounds__(256)
void transpose_v_kernel(const bf16* __restrict__ qkv, bf16* __restrict__ vT) {
  __shared__ short t[64][72];
  const int bjt = blockIdx.x;   // bj tile (0..127)
  const int ht  = blockIdx.y;   // h  tile (0..15)
  const int tid = threadIdx.x;
  #pragma unroll
  for (int u = 0; u < 2; ++u) {
    const int idx = tid + u * 256;       // 0..511
    const int row = idx >> 3;            // bj local 0..63
    const int c8  = (idx & 7) * 8;       // h local
    uint4 val = *(const uint4*)((const unsigned short*)qkv
                 + (size_t)(bjt * 64 + row) * 3072 + 2048 + ht * 64 + c8);
    *(uint4*)&t[row][c8] = val;
  }
  __syncthreads();
  #pragma unroll
  for (int u = 0; u < 2; ++u) {
    const int idx = tid + u * 256;
    const int hr  = idx >> 3;            // h local 0..63
    const int c8  = (idx & 7) * 8;       // bj local
    union { uint4 v; unsigned short s[8]; } o;
    #pragma unroll
    for (int e = 0; e < 8; ++e) o.s[e] = (unsigned short)t[c8 + e][hr];
    *(uint4*)((unsigned short*)vT + (size_t)(ht * 64 + hr) * 8192 + bjt * 64 + c8) = o.v;
  }
}

// ---------------------------------------------------------------------------
// Flash attention with banded rel-pos scores. One block = 128 Q-rows of one
// (b,n); 8 waves, each owning 16 Q-rows. Iterates causal j-tiles of 64.
// S = 0.125*(Qw·K^T + shuffle-gather(Qr·RKband^T)); online softmax; O += P·V.
// RK band lives in a 256-row RING (global row r -> ring row r&255): per tile
// only the 64 NEW rows are staged (1 gload/wave), issued right after the
// arrival barrier — target slots are outside the current read window, so
// the load hides under the whole tile compute. K/V staged per tile as before.
// q,k come from merged qkv [b*2048+i][3072] (q cols 0.., k cols 1024..).
// Layouts: vT [n*64+d][b*2048+j]; rk [m][n*64+d]; av out [b*2048+i][n*64+d].
// ---------------------------------------------------------------------------
__global__ __launch_bounds__(512, 4)
void flash_attn_kernel(const bf16* __restrict__ qkv,
                       const bf16* __restrict__ vT, const bf16* __restrict__ rk,
                       const bf16* __restrict__ rwb, const bf16* __restrict__ rrb,
                       bf16* __restrict__ av) {
  const int bx = blockIdx.x;
  const int bn = bx & 63;
  const int p  = 15 - (bx >> 6);      // heavy chunks dispatched first
  const int b  = bn >> 4, n = bn & 15;
  const int i0 = p * 128;
  const int tid = threadIdx.x, lane = tid & 63, wv = tid >> 6;  // wv 0..7
  const int quad = lane >> 4, c = lane & 15;

  __shared__ short Ks[64 * 64];        //  8192 B  K tile  [j][d]  (swizzled)
  __shared__ short VTs[64 * 64];       //  8192 B  V^T tile [d][j] (swizzled)
  __shared__ short RKs[256 * 64];      // 32768 B  rk band RING (swizzled)
  __shared__ short Ps[8][16 * 72];     // 18432 B  per-wave P (A-frag layout)
                                       //  total 67584 B -> 2 blocks/CU

  // staging lane geometry: 8 rows x 8 col-segments of 16B per wave-instr;
  // global source col pre-swizzled so linear LDS dest = XOR-swizzled tile
  const int srow = lane >> 3;                    // 0..7
  const int scol = ((lane & 7) ^ srow) * 8;      // shorts (16B units)
  // fragment-read swizzle (shorts): byte ^= (row&7)<<4 ; ring keeps row&7
  // invariant (ring base multiple of 64), so rsw from c is still correct.
  const int rsw = (c & 7) << 3;

  const unsigned short* kbase  = (const unsigned short*)qkv + ((size_t)b * 2048) * 3072 + 1024 + n * 64;
  const unsigned short* vbase  = (const unsigned short*)vT + ((size_t)(n * 64)) * 8192 + b * 2048;
  const unsigned short* rkbase = (const unsigned short*)rk + n * 64;

  auto stage_kv = [&](int j0) {
    const int row = wv * 8 + srow;
    const unsigned short* gk = kbase + (size_t)(j0 + row) * 3072 + scol;
    __builtin_amdgcn_global_load_lds(
        (const __attribute__((address_space(1))) void*)gk,
        (__attribute__((address_space(3))) void*)(Ks + wv * 512), 16, 0, 0);
    const unsigned short* gv = vbase + (size_t)row * 8192 + j0 + scol;
    __builtin_amdgcn_global_load_lds(
        (const __attribute__((address_space(1))) void*)gv,
        (__attribute__((address_space(3))) void*)(VTs + wv * 512), 16, 0, 0);
  };
  auto stage_rk = [&](int base) {        // base multiple of 64
    const int slot = (base >> 6) & 3;    // ring slot 0..3
    int rr = base + wv * 8 + srow;
    rr = rr < 2047 ? rr : 2047;          // clamp: masked-only positions
    const unsigned short* gr = rkbase + (size_t)rr * 1024 + scol;
    __builtin_amdgcn_global_load_lds(
        (const __attribute__((address_space(1))) void*)gr,
        (__attribute__((address_space(3))) void*)(RKs + (slot * 8 + wv) * 512), 16, 0, 0);
  };

  // Q fragments (registers), biases pre-added
  bf16x8 qwf[2], qrf[2];
  {
    const unsigned short* qp  = (const unsigned short*)qkv +
        ((size_t)(b * 2048 + i0 + wv * 16 + c)) * 3072 + n * 64;
    const unsigned short* wbp = (const unsigned short*)rwb + n * 64;
    const unsigned short* rbp = (const unsigned short*)rrb + n * 64;
    #pragma unroll
    for (int ch = 0; ch < 2; ++ch) {
      const int off = ch * 32 + quad * 8;
      uint4 tq = *(const uint4*)(qp + off);
      uint4 tw = *(const uint4*)(wbp + off);
      uint4 tr = *(const uint4*)(rbp + off);
      qwf[ch] = addpack(tq, tw);
      qrf[ch] = addpack(tq, tr);
    }
  }

  f32x4 O[4] = {};
  float m_i[4] = {-INFINITY, -INFINITY, -INFINITY, -INFINITY};
  float l_i[4] = {0.f, 0.f, 0.f, 0.f};

  const int gbase = 112 - wv * 16;    // per-wave band window base (0..112)
  const int cb0   = 1920 - i0;        // band start at jt=0 (multiple of 64, >=0)
  short* pw = &Ps[wv][0];

  // prologue: K/V for tile 0, RK rows [cb0, cb0+192)
  stage_kv(0);
  stage_rk(cb0);
  stage_rk(cb0 + 64);
  stage_rk(cb0 + 128);

  const int ntiles = 2 * p + 2;       // j-tiles: 0 .. 2p+1
  for (int jt = 0; jt < ntiles; ++jt) {
    const int j0 = jt * 64;
    const int cb = cb0 + j0;           // band start row this tile

    __syncthreads();   // (a) staged tiles visible to all waves (vmcnt drained)

    // early-issue the NEXT tile's new RK chunk: ring slots [cb+192, cb+256)
    // are outside this tile's read window [cb, cb+192) -> safe to overwrite;
    // latency hides under the whole tile compute, drained by next (a).
    if (jt + 1 < ntiles) stage_rk(cb + 192);

    // wave-uniform skip: all 16 rows of this wave causally masked
    if (i0 + wv * 16 + 15 >= j0) {
      // --- AC = Qw @ K^T  (16x64 per wave) ---
      f32x4 S[4] = {};
      __builtin_amdgcn_s_setprio(1);
      #pragma unroll
      for (int ch = 0; ch < 2; ++ch) {
        #pragma unroll
        for (int t = 0; t < 4; ++t) {
          bf16x8 bk = *(const bf16x8*)(const void*)
              &Ks[(t * 16 + c) * 64 + ((ch * 32 + quad * 8) ^ rsw)];
          S[t] = __builtin_amdgcn_mfma_f32_16x16x32_bf16(qwf[ch], bk, S[t], 0, 0, 0);
        }
      }
      // --- G = Qr @ RKband^T, 80-wide per-wave window (ring-indexed) ---
      f32x4 G[5] = {};
      #pragma unroll
      for (int ch = 0; ch < 2; ++ch) {
        #pragma unroll
        for (int t = 0; t < 5; ++t) {
          const int ring = (cb + gbase + t * 16 + c) & 255;
          bf16x8 br = *(const bf16x8*)(const void*)
              &RKs[ring * 64 + ((ch * 32 + quad * 8) ^ rsw)];
          G[t] = __builtin_amdgcn_mfma_f32_16x16x32_bf16(qrf[ch], br, G[t], 0, 0, 0);
        }
      }
      __builtin_amdgcn_s_setprio(0);

      // --- band gather via in-quad shuffles + scale/mask + online softmax ---
      float alpha[4];
      #pragma unroll
      for (int rg = 0; rg < 4; ++rg) {
        const int r  = quad * 4 + rg;          // local row 0..15
        const int ig = i0 + wv * 16 + r;       // global i
        const int offset = c + 15 - r;         // 0..30
        const int srcl = quad * 16 + (offset & 15);
        float gs[5];
        #pragma unroll
        for (int tt = 0; tt < 5; ++tt) gs[tt] = __shfl(G[tt][rg], srcl, 64);
        float v[4];
        #pragma unroll
        for (int u = 0; u < 4; ++u) {
          const float bd = (offset < 16) ? gs[u] : gs[u + 1];
          float s = 0.125f * (S[u][rg] + bd);
          if (j0 + u * 16 + c > ig) s = -INFINITY;
          v[u] = s;
        }
        float rmax = rowMax16(fmaxf(fmaxf(v[0], v[1]), fmaxf(v[2], v[3])));
        const float mn = fmaxf(m_i[rg], rmax);
        alpha[rg] = __expf(m_i[rg] - mn);      // first iter: exp(-inf)=0
        float rs = 0.f;
        #pragma unroll
        for (int u = 0; u < 4; ++u) {
          float p2 = __expf(v[u] - mn);
          rs += p2;
          pw[r * 72 + u * 16 + c] = (short)f2b_u(p2);
        }
        rs = rowSum16(rs);
        l_i[rg] = l_i[rg] * alpha[rg] + rs;
        m_i[rg] = mn;
      }
      #pragma unroll
      for (int t = 0; t < 4; ++t)
        #pragma unroll
        for (int rg = 0; rg < 4; ++rg)
          O[t][rg] *= alpha[rg];

      // --- O += P @ V --- (P via per-wave LDS round-trip; in-wave ordered)
      __builtin_amdgcn_s_setprio(1);
      #pragma unroll
      for (int ch = 0; ch < 2; ++ch) {
        bf16x8 ap = *(const bf16x8*)(const void*)&Ps[wv][c * 72 + ch * 32 + quad * 8];
        #pragma unroll
        for (int t = 0; t < 4; ++t) {
          bf16x8 bv2 = *(const bf16x8*)(const void*)
              &VTs[(t * 16 + c) * 64 + ((ch * 32 + quad * 8) ^ rsw)];
          O[t] = __builtin_amdgcn_mfma_f32_16x16x32_bf16(ap, bv2, O[t], 0, 0, 0);
        }
      }
      __builtin_amdgcn_s_setprio(0);
    }
    __syncthreads();   // (b) all waves done reading K/V (+RK window)
    if (jt + 1 < ntiles) stage_kv(j0 + 64);   // K/V for next tile
  }

  // epilogue: av[b*2048+i][n*64+d] bf16
  unsigned short* avp = (unsigned short*)av;
  #pragma unroll
  for (int rg = 0; rg < 4; ++rg) {
    const float inv = 1.0f / l_i[rg];
    const int i = i0 + wv * 16 + quad * 4 + rg;
    const size_t base = ((size_t)(b * 2048 + i)) * 1024 + n * 64;
    #pragma unroll
    for (int t = 0; t < 4; ++t)
      avp[base + t * 16 + c] = (unsigned short)f2b_u(O[t][rg] * inv);
  }
}

// ---------------------------------------------------------------------------
// LayerNorm over last dim (1024): out = (x+y-mu)*rsqrt(var+eps)*g + b
// Rows are [b*2048+i] order. FINAL: permute out row to (i*4+b), fp32 when
// *flag (fp32 world) else bf16.
// ---------------------------------------------------------------------------
template<bool FINAL>
__global__ __launch_bounds__(256)
void ln_kernel(const bf16* __restrict__ x, const bf16* __restrict__ y,
               const bf16* __restrict__ g, const bf16* __restrict__ bb,
               bf16* __restrict__ o_bf, float* __restrict__ o_f32,
               const int* __restrict__ flag) {
  const size_t row = blockIdx.x;
  const int tid  = threadIdx.x;
  const int lane = tid & 63;
  const int wv   = tid >> 6;

  const uint2 ux = ((const uint2*)((const unsigned short*)x + row * 1024))[tid];
  const uint2 uy = ((const uint2*)((const unsigned short*)y + row * 1024))[tid];
  float f[4];
  f[0] = b2f(ux.x & 0xffffu) + b2f(uy.x & 0xffffu);
  f[1] = b2f(ux.x >> 16)     + b2f(uy.x >> 16);
  f[2] = b2f(ux.y & 0xffffu) + b2f(uy.y & 0xffffu);
  f[3] = b2f(ux.y >> 16)     + b2f(uy.y >> 16);

  float s  = f[0] + f[1] + f[2] + f[3];
  float s2 = f[0]*f[0] + f[1]*f[1] + f[2]*f[2] + f[3]*f[3];
  s  = waveReduceSum(s);
  s2 = waveReduceSum(s2);
  __shared__ float r1[4], r2[4];
  if (lane == 0) { r1[wv] = s; r2[wv] = s2; }
  __syncthreads();
  s  = r1[0] + r1[1] + r1[2] + r1[3];
  s2 = r2[0] + r2[1] + r2[2] + r2[3];
  const float mu   = s * (1.0f / 1024.0f);
  const float var  = s2 * (1.0f / 1024.0f) - mu * mu;
  const float rstd = rsqrtf(var + 1e-5f);

  const uint2 ug = ((const uint2*)(const void*)g)[tid];
  const uint2 ub = ((const uint2*)(const void*)bb)[tid];
  float gv[4] = { b2f(ug.x & 0xffffu), b2f(ug.x >> 16), b2f(ug.y & 0xffffu), b2f(ug.y >> 16) };
  float bv[4] = { b2f(ub.x & 0xffffu), b2f(ub.x >> 16), b2f(ub.y & 0xffffu), b2f(ub.y >> 16) };

  float vout[4];
  #pragma unroll
  for (int c2 = 0; c2 < 4; ++c2)
    vout[c2] = (f[c2] - mu) * rstd * gv[c2] + bv[c2];

  size_t orow = row;
  if (FINAL) orow = (size_t)((row & 2047) * 4 + (row >> 11));  // [b][i] -> [i][b]

  if (FINAL && *flag) {
    float4 res = { vout[0], vout[1], vout[2], vout[3] };
    ((float4*)(o_f32 + orow * 1024))[tid] = res;
  } else {
    uint2 res;
    res.x = f2b_u(vout[0]) | (f2b_u(vout[1]) << 16);
    res.y = f2b_u(vout[2]) | (f2b_u(vout[3]) << 16);
    ((uint2*)((unsigned short*)o_bf + orow * 1024))[tid] = res;
  }
}

// ---------------------------------------------------------------------------

extern "C" void kernel_launch(void* const* d_in, const int* in_sizes, int n_in,
                              void* d_out, int out_size, void* d_ws, size_t ws_size,
                              hipStream_t stream) {
  (void)in_sizes; (void)n_in; (void)out_size; (void)ws_size;

  char* ws = (char*)d_ws;
  const size_t MB = 1u << 20;
  const size_t KB = 1u << 10;

  // converted bf16 inputs [0, 48 MiB)
  bf16* wb_b = (bf16*)(ws + 0 * MB);    // w, PERMUTED to [b*2048+i][dm]
  bf16* r_b  = (bf16*)(ws + 16 * MB);
  bf16* Wq_b = (bf16*)(ws + 20 * MB);   // Wq/Wk/Wv contiguous -> merged WQKV
  bf16* Wk_b = (bf16*)(ws + 22 * MB);
  bf16* Wv_b = (bf16*)(ws + 24 * MB);
  bf16* Wr_b = (bf16*)(ws + 26 * MB);
  bf16* Wo_b = (bf16*)(ws + 28 * MB);
  bf16* W1_b = (bf16*)(ws + 30 * MB);
  bf16* W2_b = (bf16*)(ws + 38 * MB);
  char* smalls = ws + 46 * MB;
  // merged QKV bias (3072 contiguous bf16 = 6 KB) in slot 0
  bf16* bq_b  = (bf16*)(smalls + 0 * 2 * KB);
  bf16* bk_b  = (bf16*)(smalls + 1 * 2 * KB);
  bf16* bv_b  = (bf16*)(smalls + 2 * 2 * KB);
  bf16* br_b  = (bf16*)(smalls + 3 * 8 * KB);
  bf16* bo_b  = (bf16*)(smalls + 4 * 8 * KB);
  bf16* rwb_b = (bf16*)(smalls + 5 * 8 * KB);
  bf16* rrb_b = (bf16*)(smalls + 6 * 8 * KB);
  bf16* g1_b  = (bf16*)(smalls + 7 * 8 * KB);
  bf16* lb1_b = (bf16*)(smalls + 8 * 8 * KB);
  bf16* b1_b  = (bf16*)(smalls + 9 * 8 * KB);
  bf16* b2_b  = (bf16*)(smalls + 10 * 8 * KB);
  bf16* g2_b  = (bf16*)(smalls + 11 * 8 * KB);
  bf16* lb2_b = (bf16*)(smalls + 12 * 8 * KB);
  int*  flag  = (int*)(ws + 47 * MB);

  // pipeline buffers, reused (high-water 144 MiB)
  bf16* qkv_ws  = (bf16*)(ws + 48 * MB);   // [b*2048+i][3072] (q|k|v)
  bf16* vT_ws   = (bf16*)(ws + 96 * MB);   // [h][b*2048+j]
  bf16* rk_ws   = (bf16*)(ws + 112 * MB);  // [m][h]
  bf16* av_ws   = (bf16*)(ws + 116 * MB);  // [b*2048+i][h]
  bf16* ao_ws   = (bf16*)(ws + 48 * MB);   // reuse qkv (dead after flash)
  bf16* out1_ws = (bf16*)(ws + 64 * MB);   // reuse qkv tail
  bf16* ff1_ws  = (bf16*)(ws + 80 * MB);   // 64 MiB [80,144): vT/rk/av dead after Wo
  bf16* core_ws = (bf16*)(ws + 48 * MB);   // reuse ao (dead after LN1)

  detect_kernel<<<dim3(1), dim3(256), 0, stream>>>((const unsigned*)d_in[0], flag);

  CvtTab tab;
  const int  srcidx[22] = {0,1,3,5,7,9,11,17,19, 4,6,8,10,12,13,14,15,16,18,20,21,22};
  bf16*      dsts[22]   = {wb_b,r_b,Wq_b,Wk_b,Wv_b,Wr_b,Wo_b,W1_b,W2_b,
                           bq_b,bk_b,bv_b,br_b,bo_b,rwb_b,rrb_b,g1_b,lb1_b,b1_b,b2_b,g2_b,lb2_b};
  const int  ns[22]     = {8388608,2097152,1048576,1048576,1048576,1048576,1048576,4194304,4194304,
                           1024,1024,1024,1024,1024,1024,1024,1024,1024,4096,1024,1024,1024};
  for (int s = 0; s < 22; ++s) { tab.src[s] = d_in[srcidx[s]]; tab.dst[s] = dsts[s]; tab.n[s] = ns[s]; }
  convert_kernel<<<dim3(512, 22), dim3(256), 0, stream>>>(tab, flag);

  const dim3 blk(256);

  // merged QKV projection: C[8192][3072] = wb @ [Wq;Wk;Wv]^T + [bq;bk;bv]
  gemm_bt_kernel<false><<<dim3(24, 64), blk, 0, stream>>>(wb_b, Wq_b, bq_b, qkv_ws, 8192, 3072, 1024);
  // V transpose to vT[h][bj]
  transpose_v_kernel<<<dim3(128, 16), blk, 0, stream>>>(qkv_ws, vT_ws);
  // rel-pos projection
  gemm_bt_kernel<false><<<dim3(8, 16), blk, 0, stream>>>(r_b, Wr_b, br_b, rk_ws, 2048, 1024, 1024);

  // flash attention: 1024 blocks of 512 threads (128 Q-rows each)
  flash_attn_kernel<<<dim3(1024), dim3(512), 0, stream>>>(qkv_ws, vT_ws, rk_ws, rwb_b, rrb_b, av_ws);

  // output projection + LN1
  gemm_bt_kernel<false><<<dim3(8, 64), blk, 0, stream>>>(av_ws, Wo_b, bo_b, ao_ws, 8192, 1024, 1024);
  ln_kernel<false><<<dim3(8192), blk, 0, stream>>>(wb_b, ao_ws, g1_b, lb1_b, out1_ws, nullptr, flag);

  // FFN (single-shot) + final LN (permutes rows back to [i][b], fp32 out)
  gemm_bt_kernel<true ><<<dim3(32, 64), blk, 0, stream>>>(out1_ws, W1_b, b1_b, ff1_ws, 8192, 4096, 1024);
  gemm_bt_kernel<false><<<dim3(8, 64), blk, 0, stream>>>(ff1_ws, W2_b, b2_b, core_ws, 8192, 1024, 4096);
  ln_kernel<true><<<dim3(8192), blk, 0, stream>>>(out1_ws, core_ws, g2_b, lb2_b, (bf16*)d_out, (float*)d_out, flag);
}

// Round 8
// 680.397 us; speedup vs baseline: 1.0651x; 1.0507x over previous
//
#include <hip/hip_runtime.h>
#include <hip/hip_bf16.h>
#include <cstdint>
#include <math.h>

// ---------------------------------------------------------------------------
// MemTransformerLM (Transformer-XL layer) on MI355X / gfx950.
// Round 14:
//  - GEMM launch_bounds back to (256,2) (R7's (256,3) regressed ~20us:
//    VGPR cap 168 hurt scheduling more than the 3rd block helped).
//  - GEMM T1: XCD-aware bijective chunked block swizzle (all grids %8==0)
//    -> contiguous (by,bx) chunk per XCD, A-panels L2-resident.
//  - GEMM coalesced epilogue: C tile bounced through As/Bs (dead after
//    K-loop, exactly 128x128 bf16): 64 ds_write_b16 -> barrier -> 8
//    ds_read_b128 + 8 global_store_dwordx4 (was 64 scalar 2B stores).
//  - flash unchanged (RK ring proven: 229->208us).
// ---------------------------------------------------------------------------

using bf16 = __hip_bfloat16;
using bf16x8 = __attribute__((ext_vector_type(8))) __bf16;
using f32x4  = __attribute__((ext_vector_type(4))) float;

__device__ __forceinline__ float b2f(unsigned u) {
  union { unsigned u; float f; } x; x.u = u << 16; return x.f;
}
__device__ __forceinline__ unsigned f2b_u(float f) {
  bf16 h = __float2bfloat16(f);
  return (unsigned)__builtin_bit_cast(unsigned short, h);
}

__device__ __forceinline__ float waveReduceSum(float x) {
  #pragma unroll
  for (int o = 32; o > 0; o >>= 1) x += __shfl_down(x, o, 64);
  return x;
}

// DPP move within 16-lane rows (VALU pipe — keeps LDS pipe free)
template<int CTRL>
__device__ __forceinline__ float dppMovF(float x) {
  return __builtin_bit_cast(float,
      __builtin_amdgcn_mov_dpp(__builtin_bit_cast(int, x), CTRL, 0xf, 0xf, true));
}
// reduce across the 16 lanes of each row via row_ror 1,2,4,8 (rotation tree)
__device__ __forceinline__ float rowMax16(float x) {
  x = fmaxf(x, dppMovF<0x121>(x));
  x = fmaxf(x, dppMovF<0x122>(x));
  x = fmaxf(x, dppMovF<0x124>(x));
  x = fmaxf(x, dppMovF<0x128>(x));
  return x;
}
__device__ __forceinline__ float rowSum16(float x) {
  x += dppMovF<0x121>(x);
  x += dppMovF<0x122>(x);
  x += dppMovF<0x124>(x);
  x += dppMovF<0x128>(x);
  return x;
}

// add two bf16x8 (as uint4 bit-patterns) in f32, repack to bf16x8
__device__ __forceinline__ bf16x8 addpack(uint4 a, uint4 b) {
  union { uint4 u; unsigned short s[8]; } ua, ub;
  ua.u = a; ub.u = b;
  union { bf16x8 v; unsigned short s[8]; } r;
  #pragma unroll
  for (int i = 0; i < 8; ++i) r.s[i] = (unsigned short)f2b_u(b2f(ua.s[i]) + b2f(ub.s[i]));
  return r.v;
}

// ---------------------------------------------------------------------------
// dtype detect (fp32 vs bf16 inputs) — parallel version (256 thr x 4 elems).
// ---------------------------------------------------------------------------
__global__ __launch_bounds__(256)
void detect_kernel(const unsigned* __restrict__ wraw, int* __restrict__ flag) {
  const int tid = threadIdx.x;
  int v = 0;
  #pragma unroll
  for (int u = 0; u < 4; ++u) {
    unsigned e = (wraw[tid * 4 + u] >> 7) & 0xffu;
    v += (e >= 0x5Au && e <= 0x8Au) ? 1 : 0;
  }
  #pragma unroll
  for (int o = 32; o > 0; o >>= 1) v += __shfl_down(v, o, 64);
  __shared__ int acc[4];
  if ((tid & 63) == 0) acc[tid >> 6] = v;
  __syncthreads();
  if (tid == 0) *flag = (acc[0] + acc[1] + acc[2] + acc[3] < 512) ? 1 : 0;
}

struct CvtTab {
  const void* src[22];
  bf16*       dst[22];
  int         n[22];
};

// seg 0 (= w) is written PERMUTED to batch-major "wb" layout:
// src element e = (i*4+b)*1024 + d  ->  dst (b*2048+i)*1024 + d
__global__ __launch_bounds__(256)
void convert_kernel(CvtTab tab, const int* __restrict__ flag) {
  const int seg = blockIdx.y;
  const int n   = tab.n[seg];
  const int f   = *flag;
  unsigned short* dst = (unsigned short*)tab.dst[seg];
  const int stride = gridDim.x * blockDim.x;
  for (int i = blockIdx.x * blockDim.x + threadIdx.x; i < n; i += stride) {
    float val;
    if (f) val = ((const float*)tab.src[seg])[i];
    else   val = b2f(((const unsigned short*)tab.src[seg])[i]);
    int di = i;
    if (seg == 0) {
      int ii = i >> 12, bb = (i >> 10) & 3, dd = i & 1023;
      di = (bb << 21) | (ii << 10) | dd;
    }
    dst[di] = (unsigned short)f2b_u(val);
  }
}

// ---------------------------------------------------------------------------
// Generic bf16 GEMM: C[M,N] = A[M,K] @ B[N,K]^T + bias, optional ReLU.
// 128x128 tile, BK=32, 4 waves (2x2). Double-buffered LDS (32 KB), ONE
// barrier per K-step; stage(t+1) issued before compute(t).
// T1: bijective XCD chunked block swizzle (grid size % 8 == 0 for all our
// shapes) — each XCD gets a contiguous (by,bx) chunk -> A panels L2-hit.
// Epilogue: C tile bounced through As/Bs (dead, exactly 128x128 bf16) for
// fully-coalesced dwordx4 stores.
// ---------------------------------------------------------------------------
template<bool RELU>
__global__ __launch_bounds__(256, 2)
void gemm_bt_kernel(const bf16* __restrict__ A, const bf16* __restrict__ B,
                    const bf16* __restrict__ bias, bf16* __restrict__ C,
                    int M, int N, int K) {
  __shared__ short As[2][128 * 32];   // K-loop staging; epilogue: C rows 0-63
  __shared__ short Bs[2][128 * 32];   //                  epilogue: C rows 64-127

  const int tid  = threadIdx.x;
  const int lane = tid & 63;
  const int wv   = tid >> 6;

  // T1 XCD swizzle (nwg % 8 == 0 for all dispatches here)
  const int gx  = gridDim.x;
  const int nwg = gx * gridDim.y;
  const int id  = blockIdx.x + gx * blockIdx.y;
  const int nid = (id & 7) * (nwg >> 3) + (id >> 3);
  const int row0 = (nid / gx) * 128;
  const int col0 = (nid % gx) * 128;

  const int wm = (wv & 1) * 64;
  const int wn = (wv >> 1) * 64;
  const int lm = lane & 15;
  const int kq = lane >> 4;

  const int st_r = lane >> 2;        // staging: lane -> row seg*16 + l/4
  const int st_c = (lane & 3) * 8;   //          col (l%4)*8 elements (16 B)

  auto stage = [&](int buf, int k0) {
    #pragma unroll
    for (int cc = 0; cc < 2; ++cc) {
      const int seg = wv * 2 + cc;
      const int r   = seg * 16 + st_r;
      const bf16* ga = A + (size_t)(row0 + r) * K + k0 + st_c;
      const bf16* gb = B + (size_t)(col0 + r) * K + k0 + st_c;
      __builtin_amdgcn_global_load_lds(
          (const __attribute__((address_space(1))) void*)ga,
          (__attribute__((address_space(3))) void*)(&As[buf][seg * 512]), 16, 0, 0);
      __builtin_amdgcn_global_load_lds(
          (const __attribute__((address_space(1))) void*)gb,
          (__attribute__((address_space(3))) void*)(&Bs[buf][seg * 512]), 16, 0, 0);
    }
  };

  f32x4 acc[4][4] = {};
  const int nk = K >> 5;

  stage(0, 0);
  __syncthreads();            // buf0 staged (vmcnt drained by barrier)

  int cur = 0;
  for (int t = 0; t < nk; ++t) {
    if (t + 1 < nk) stage(cur ^ 1, (t + 1) * 32);   // issue next: hides under compute

    bf16x8 af[4], bfr[4];
    #pragma unroll
    for (int tt = 0; tt < 4; ++tt) {
      af[tt]  = *(const bf16x8*)(const void*)(&As[cur][(wm + tt * 16 + lm) * 32 + kq * 8]);
      bfr[tt] = *(const bf16x8*)(const void*)(&Bs[cur][(wn + tt * 16 + lm) * 32 + kq * 8]);
    }
    #pragma unroll
    for (int mt = 0; mt < 4; ++mt)
      #pragma unroll
      for (int nt = 0; nt < 4; ++nt)
        acc[mt][nt] = __builtin_amdgcn_mfma_f32_16x16x32_bf16(
            af[mt], bfr[nt], acc[mt][nt], 0, 0, 0);

    __syncthreads();          // next staging complete + all reads of cur done
    cur ^= 1;
  }

  // ---- coalesced epilogue: bounce C tile (bf16) through As/Bs ----
  // wave (wm) writes its 64x128-half rows: waves 0,2 (wm=0) -> As; 1,3 -> Bs.
  short* cl_w = (wm == 0) ? (short*)As : (short*)Bs;
  const unsigned short* bias_us = (const unsigned short*)bias;
  #pragma unroll
  for (int nt = 0; nt < 4; ++nt) {
    const int col = wn + nt * 16 + lm;            // tile-local col 0..127
    const float bvc = b2f(bias_us[col0 + col]);
    #pragma unroll
    for (int mt = 0; mt < 4; ++mt) {
      #pragma unroll
      for (int rg = 0; rg < 4; ++rg) {
        const int rloc = mt * 16 + kq * 4 + rg;   // 0..63 within half
        float val = acc[mt][nt][rg] + bvc;
        if (RELU) val = fmaxf(val, 0.0f);
        cl_w[rloc * 128 + col] = (short)f2b_u(val);
      }
    }
  }
  __syncthreads();
  // read back: waves 0,1 drain As (tile rows 0-63), waves 2,3 drain Bs.
  const short* cl_r = (wv < 2) ? (const short*)As : (const short*)Bs;
  unsigned short* Cus = (unsigned short*)C;
  #pragma unroll
  for (int k = 0; k < 8; ++k) {
    const int rloc = (wv & 1) * 32 + k * 4 + (lane >> 4);   // 0..63 in half
    const int trow = (wv >> 1) * 64 + rloc;                 // 0..127 in tile
    uint4 vv = *(const uint4*)(cl_r + rloc * 128 + (lane & 15) * 8);
    *(uint4*)(Cus + (size_t)(row0 + trow) * N + col0 + (lane & 15) * 8) = vv;
  }
}

// ---------------------------------------------------------------------------
// V transpose: vT[n*64+d][b*2048+j] = qkv[b*2048+j][2048 + n*64+d]
// 64x64 tiles via padded LDS. grid (128, 16), 256 threads.
// ---------------------------------------------------------------------------
__global__ __launch_bounds__(256)
void transpose_v_kernel(const bf16* __restrict__ qkv, bf16* __restrict__ vT) {
  __shared__ short t[64][72];
  const int bjt = blockIdx.x;   // bj tile (0..127)
  const int ht  = blockIdx.y;   // h  tile (0..15)
  const int tid = threadIdx.x;
  #pragma unroll
  for (int u = 0; u < 2; ++u) {
    const int idx = tid + u * 256;       // 0..511
    const int row = idx >> 3;            // bj local 0..63
    const int c8  = (idx & 7) * 8;       // h local
    uint4 val = *(const uint4*)((const unsigned short*)qkv
                 + (size_t)(bjt * 64 + row) * 3072 + 2048 + ht * 64 + c8);
    *(uint4*)&t[row][c8] = val;
  }
  __syncthreads();
  #pragma unroll
  for (int u = 0; u < 2; ++u) {
    const int idx = tid + u * 256;
    const int hr  = idx >> 3;            // h local 0..63
    const int c8  = (idx & 7) * 8;       // bj local
    union { uint4 v; unsigned short s[8]; } o;
    #pragma unroll
    for (int e = 0; e < 8; ++e) o.s[e] = (unsigned short)t[c8 + e][hr];
    *(uint4*)((unsigned short*)vT + (size_t)(ht * 64 + hr) * 8192 + bjt * 64 + c8) = o.v;
  }
}

// ---------------------------------------------------------------------------
// Flash attention with banded rel-pos scores. One block = 128 Q-rows of one
// (b,n); 8 waves, each owning 16 Q-rows. Iterates causal j-tiles of 64.
// S = 0.125*(Qw·K^T + shuffle-gather(Qr·RKband^T)); online softmax; O += P·V.
// RK band lives in a 256-row RING (global row r -> ring row r&255): per tile
// only the 64 NEW rows are staged (1 gload/wave), issued right after the
// arrival barrier — target slots are outside the current read window, so
// the load hides under the whole tile compute. K/V staged per tile as before.
// q,k come from merged qkv [b*2048+i][3072] (q cols 0.., k cols 1024..).
// Layouts: vT [n*64+d][b*2048+j]; rk [m][n*64+d]; av out [b*2048+i][n*64+d].
// ---------------------------------------------------------------------------
__global__ __launch_bounds__(512, 4)
void flash_attn_kernel(const bf16* __restrict__ qkv,
                       const bf16* __restrict__ vT, const bf16* __restrict__ rk,
                       const bf16* __restrict__ rwb, const bf16* __restrict__ rrb,
                       bf16* __restrict__ av) {
  const int bx = blockIdx.x;
  const int bn = bx & 63;
  const int p  = 15 - (bx >> 6);      // heavy chunks dispatched first
  const int b  = bn >> 4, n = bn & 15;
  const int i0 = p * 128;
  const int tid = threadIdx.x, lane = tid & 63, wv = tid >> 6;  // wv 0..7
  const int quad = lane >> 4, c = lane & 15;

  __shared__ short Ks[64 * 64];        //  8192 B  K tile  [j][d]  (swizzled)
  __shared__ short VTs[64 * 64];       //  8192 B  V^T tile [d][j] (swizzled)
  __shared__ short RKs[256 * 64];      // 32768 B  rk band RING (swizzled)
  __shared__ short Ps[8][16 * 72];     // 18432 B  per-wave P (A-frag layout)
                                       //  total 67584 B -> 2 blocks/CU

  // staging lane geometry: 8 rows x 8 col-segments of 16B per wave-instr;
  // global source col pre-swizzled so linear LDS dest = XOR-swizzled tile
  const int srow = lane >> 3;                    // 0..7
  const int scol = ((lane & 7) ^ srow) * 8;      // shorts (16B units)
  // fragment-read swizzle (shorts): byte ^= (row&7)<<4 ; ring keeps row&7
  // invariant (ring base multiple of 64), so rsw from c is still correct.
  const int rsw = (c & 7) << 3;

  const unsigned short* kbase  = (const unsigned short*)qkv + ((size_t)b * 2048) * 3072 + 1024 + n * 64;
  const unsigned short* vbase  = (const unsigned short*)vT + ((size_t)(n * 64)) * 8192 + b * 2048;
  const unsigned short* rkbase = (const unsigned short*)rk + n * 64;

  auto stage_kv = [&](int j0) {
    const int row = wv * 8 + srow;
    const unsigned short* gk = kbase + (size_t)(j0 + row) * 3072 + scol;
    __builtin_amdgcn_global_load_lds(
        (const __attribute__((address_space(1))) void*)gk,
        (__attribute__((address_space(3))) void*)(Ks + wv * 512), 16, 0, 0);
    const unsigned short* gv = vbase + (size_t)row * 8192 + j0 + scol;
    __builtin_amdgcn_global_load_lds(
        (const __attribute__((address_space(1))) void*)gv,
        (__attribute__((address_space(3))) void*)(VTs + wv * 512), 16, 0, 0);
  };
  auto stage_rk = [&](int base) {        // base multiple of 64
    const int slot = (base >> 6) & 3;    // ring slot 0..3
    int rr = base + wv * 8 + srow;
    rr = rr < 2047 ? rr : 2047;          // clamp: masked-only positions
    const unsigned short* gr = rkbase + (size_t)rr * 1024 + scol;
    __builtin_amdgcn_global_load_lds(
        (const __attribute__((address_space(1))) void*)gr,
        (__attribute__((address_space(3))) void*)(RKs + (slot * 8 + wv) * 512), 16, 0, 0);
  };

  // Q fragments (registers), biases pre-added
  bf16x8 qwf[2], qrf[2];
  {
    const unsigned short* qp  = (const unsigned short*)qkv +
        ((size_t)(b * 2048 + i0 + wv * 16 + c)) * 3072 + n * 64;
    const unsigned short* wbp = (const unsigned short*)rwb + n * 64;
    const unsigned short* rbp = (const unsigned short*)rrb + n * 64;
    #pragma unroll
    for (int ch = 0; ch < 2; ++ch) {
      const int off = ch * 32 + quad * 8;
      uint4 tq = *(const uint4*)(qp + off);
      uint4 tw = *(const uint4*)(wbp + off);
      uint4 tr = *(const uint4*)(rbp + off);
      qwf[ch] = addpack(tq, tw);
      qrf[ch] = addpack(tq, tr);
    }
  }

  f32x4 O[4] = {};
  float m_i[4] = {-INFINITY, -INFINITY, -INFINITY, -INFINITY};
  float l_i[4] = {0.f, 0.f, 0.f, 0.f};

  const int gbase = 112 - wv * 16;    // per-wave band window base (0..112)
  const int cb0   = 1920 - i0;        // band start at jt=0 (multiple of 64, >=0)
  short* pw = &Ps[wv][0];

  // prologue: K/V for tile 0, RK rows [cb0, cb0+192)
  stage_kv(0);
  stage_rk(cb0);
  stage_rk(cb0 + 64);
  stage_rk(cb0 + 128);

  const int ntiles = 2 * p + 2;       // j-tiles: 0 .. 2p+1
  for (int jt = 0; jt < ntiles; ++jt) {
    const int j0 = jt * 64;
    const int cb = cb0 + j0;           // band start row this tile

    __syncthreads();   // (a) staged tiles visible to all waves (vmcnt drained)

    // early-issue the NEXT tile's new RK chunk: ring slots [cb+192, cb+256)
    // are outside this tile's read window [cb, cb+192) -> safe to overwrite;
    // latency hides under the whole tile compute, drained by next (a).
    if (jt + 1 < ntiles) stage_rk(cb + 192);

    // wave-uniform skip: all 16 rows of this wave causally masked
    if (i0 + wv * 16 + 15 >= j0) {
      // --- AC = Qw @ K^T  (16x64 per wave) ---
      f32x4 S[4] = {};
      __builtin_amdgcn_s_setprio(1);
      #pragma unroll
      for (int ch = 0; ch < 2; ++ch) {
        #pragma unroll
        for (int t = 0; t < 4; ++t) {
          bf16x8 bk = *(const bf16x8*)(const void*)
              &Ks[(t * 16 + c) * 64 + ((ch * 32 + quad * 8) ^ rsw)];
          S[t] = __builtin_amdgcn_mfma_f32_16x16x32_bf16(qwf[ch], bk, S[t], 0, 0, 0);
        }
      }
      // --- G = Qr @ RKband^T, 80-wide per-wave window (ring-indexed) ---
      f32x4 G[5] = {};
      #pragma unroll
      for (int ch = 0; ch < 2; ++ch) {
        #pragma unroll
        for (int t = 0; t < 5; ++t) {
          const int ring = (cb + gbase + t * 16 + c) & 255;
          bf16x8 br = *(const bf16x8*)(const void*)
              &RKs[ring * 64 + ((ch * 32 + quad * 8) ^ rsw)];
          G[t] = __builtin_amdgcn_mfma_f32_16x16x32_bf16(qrf[ch], br, G[t], 0, 0, 0);
        }
      }
      __builtin_amdgcn_s_setprio(0);

      // --- band gather via in-quad shuffles + scale/mask + online softmax ---
      float alpha[4];
      #pragma unroll
      for (int rg = 0; rg < 4; ++rg) {
        const int r  = quad * 4 + rg;          // local row 0..15
        const int ig = i0 + wv * 16 + r;       // global i
        const int offset = c + 15 - r;         // 0..30
        const int srcl = quad * 16 + (offset & 15);
        float gs[5];
        #pragma unroll
        for (int tt = 0; tt < 5; ++tt) gs[tt] = __shfl(G[tt][rg], srcl, 64);
        float v[4];
        #pragma unroll
        for (int u = 0; u < 4; ++u) {
          const float bd = (offset < 16) ? gs[u] : gs[u + 1];
          float s = 0.125f * (S[u][rg] + bd);
          if (j0 + u * 16 + c > ig) s = -INFINITY;
          v[u] = s;
        }
        float rmax = rowMax16(fmaxf(fmaxf(v[0], v[1]), fmaxf(v[2], v[3])));
        const float mn = fmaxf(m_i[rg], rmax);
        alpha[rg] = __expf(m_i[rg] - mn);      // first iter: exp(-inf)=0
        float rs = 0.f;
        #pragma unroll
        for (int u = 0; u < 4; ++u) {
          float p2 = __expf(v[u] - mn);
          rs += p2;
          pw[r * 72 + u * 16 + c] = (short)f2b_u(p2);
        }
        rs = rowSum16(rs);
        l_i[rg] = l_i[rg] * alpha[rg] + rs;
        m_i[rg] = mn;
      }
      #pragma unroll
      for (int t = 0; t < 4; ++t)
        #pragma unroll
        for (int rg = 0; rg < 4; ++rg)
          O[t][rg] *= alpha[rg];

      // --- O += P @ V --- (P via per-wave LDS round-trip; in-wave ordered)
      __builtin_amdgcn_s_setprio(1);
      #pragma unroll
      for (int ch = 0; ch < 2; ++ch) {
        bf16x8 ap = *(const bf16x8*)(const void*)&Ps[wv][c * 72 + ch * 32 + quad * 8];
        #pragma unroll
        for (int t = 0; t < 4; ++t) {
          bf16x8 bv2 = *(const bf16x8*)(const void*)
              &VTs[(t * 16 + c) * 64 + ((ch * 32 + quad * 8) ^ rsw)];
          O[t] = __builtin_amdgcn_mfma_f32_16x16x32_bf16(ap, bv2, O[t], 0, 0, 0);
        }
      }
      __builtin_amdgcn_s_setprio(0);
    }
    __syncthreads();   // (b) all waves done reading K/V (+RK window)
    if (jt + 1 < ntiles) stage_kv(j0 + 64);   // K/V for next tile
  }

  // epilogue: av[b*2048+i][n*64+d] bf16
  unsigned short* avp = (unsigned short*)av;
  #pragma unroll
  for (int rg = 0; rg < 4; ++rg) {
    const float inv = 1.0f / l_i[rg];
    const int i = i0 + wv * 16 + quad * 4 + rg;
    const size_t base = ((size_t)(b * 2048 + i)) * 1024 + n * 64;
    #pragma unroll
    for (int t = 0; t < 4; ++t)
      avp[base + t * 16 + c] = (unsigned short)f2b_u(O[t][rg] * inv);
  }
}

// ---------------------------------------------------------------------------
// LayerNorm over last dim (1024): out = (x+y-mu)*rsqrt(var+eps)*g + b
// Rows are [b*2048+i] order. FINAL: permute out row to (i*4+b), fp32 when
// *flag (fp32 world) else bf16.
// ---------------------------------------------------------------------------
template<bool FINAL>
__global__ __launch_bounds__(256)
void ln_kernel(const bf16* __restrict__ x, const bf16* __restrict__ y,
               const bf16* __restrict__ g, const bf16* __restrict__ bb,
               bf16* __restrict__ o_bf, float* __restrict__ o_f32,
               const int* __restrict__ flag) {
  const size_t row = blockIdx.x;
  const int tid  = threadIdx.x;
  const int lane = tid & 63;
  const int wv   = tid >> 6;

  const uint2 ux = ((const uint2*)((const unsigned short*)x + row * 1024))[tid];
  const uint2 uy = ((const uint2*)((const unsigned short*)y + row * 1024))[tid];
  float f[4];
  f[0] = b2f(ux.x & 0xffffu) + b2f(uy.x & 0xffffu);
  f[1] = b2f(ux.x >> 16)     + b2f(uy.x >> 16);
  f[2] = b2f(ux.y & 0xffffu) + b2f(uy.y & 0xffffu);
  f[3] = b2f(ux.y >> 16)     + b2f(uy.y >> 16);

  float s  = f[0] + f[1] + f[2] + f[3];
  float s2 = f[0]*f[0] + f[1]*f[1] + f[2]*f[2] + f[3]*f[3];
  s  = waveReduceSum(s);
  s2 = waveReduceSum(s2);
  __shared__ float r1[4], r2[4];
  if (lane == 0) { r1[wv] = s; r2[wv] = s2; }
  __syncthreads();
  s  = r1[0] + r1[1] + r1[2] + r1[3];
  s2 = r2[0] + r2[1] + r2[2] + r2[3];
  const float mu   = s * (1.0f / 1024.0f);
  const float var  = s2 * (1.0f / 1024.0f) - mu * mu;
  const float rstd = rsqrtf(var + 1e-5f);

  const uint2 ug = ((const uint2*)(const void*)g)[tid];
  const uint2 ub = ((const uint2*)(const void*)bb)[tid];
  float gv[4] = { b2f(ug.x & 0xffffu), b2f(ug.x >> 16), b2f(ug.y & 0xffffu), b2f(ug.y >> 16) };
  float bv[4] = { b2f(ub.x & 0xffffu), b2f(ub.x >> 16), b2f(ub.y & 0xffffu), b2f(ub.y >> 16) };

  float vout[4];
  #pragma unroll
  for (int c2 = 0; c2 < 4; ++c2)
    vout[c2] = (f[c2] - mu) * rstd * gv[c2] + bv[c2];

  size_t orow = row;
  if (FINAL) orow = (size_t)((row & 2047) * 4 + (row >> 11));  // [b][i] -> [i][b]

  if (FINAL && *flag) {
    float4 res = { vout[0], vout[1], vout[2], vout[3] };
    ((float4*)(o_f32 + orow * 1024))[tid] = res;
  } else {
    uint2 res;
    res.x = f2b_u(vout[0]) | (f2b_u(vout[1]) << 16);
    res.y = f2b_u(vout[2]) | (f2b_u(vout[3]) << 16);
    ((uint2*)((unsigned short*)o_bf + orow * 1024))[tid] = res;
  }
}

// ---------------------------------------------------------------------------

extern "C" void kernel_launch(void* const* d_in, const int* in_sizes, int n_in,
                              void* d_out, int out_size, void* d_ws, size_t ws_size,
                              hipStream_t stream) {
  (void)in_sizes; (void)n_in; (void)out_size; (void)ws_size;

  char* ws = (char*)d_ws;
  const size_t MB = 1u << 20;
  const size_t KB = 1u << 10;

  // converted bf16 inputs [0, 48 MiB)
  bf16* wb_b = (bf16*)(ws + 0 * MB);    // w, PERMUTED to [b*2048+i][dm]
  bf16* r_b  = (bf16*)(ws + 16 * MB);
  bf16* Wq_b = (bf16*)(ws + 20 * MB);   // Wq/Wk/Wv contiguous -> merged WQKV
  bf16* Wk_b = (bf16*)(ws + 22 * MB);
  bf16* Wv_b = (bf16*)(ws + 24 * MB);
  bf16* Wr_b = (bf16*)(ws + 26 * MB);
  bf16* Wo_b = (bf16*)(ws + 28 * MB);
  bf16* W1_b = (bf16*)(ws + 30 * MB);
  bf16* W2_b = (bf16*)(ws + 38 * MB);
  char* smalls = ws + 46 * MB;
  // merged QKV bias (3072 contiguous bf16 = 6 KB) in slot 0
  bf16* bq_b  = (bf16*)(smalls + 0 * 2 * KB);
  bf16* bk_b  = (bf16*)(smalls + 1 * 2 * KB);
  bf16* bv_b  = (bf16*)(smalls + 2 * 2 * KB);
  bf16* br_b  = (bf16*)(smalls + 3 * 8 * KB);
  bf16* bo_b  = (bf16*)(smalls + 4 * 8 * KB);
  bf16* rwb_b = (bf16*)(smalls + 5 * 8 * KB);
  bf16* rrb_b = (bf16*)(smalls + 6 * 8 * KB);
  bf16* g1_b  = (bf16*)(smalls + 7 * 8 * KB);
  bf16* lb1_b = (bf16*)(smalls + 8 * 8 * KB);
  bf16* b1_b  = (bf16*)(smalls + 9 * 8 * KB);
  bf16* b2_b  = (bf16*)(smalls + 10 * 8 * KB);
  bf16* g2_b  = (bf16*)(smalls + 11 * 8 * KB);
  bf16* lb2_b = (bf16*)(smalls + 12 * 8 * KB);
  int*  flag  = (int*)(ws + 47 * MB);

  // pipeline buffers, reused (high-water 144 MiB)
  bf16* qkv_ws  = (bf16*)(ws + 48 * MB);   // [b*2048+i][3072] (q|k|v)
  bf16* vT_ws   = (bf16*)(ws + 96 * MB);   // [h][b*2048+j]
  bf16* rk_ws   = (bf16*)(ws + 112 * MB);  // [m][h]
  bf16* av_ws   = (bf16*)(ws + 116 * MB);  // [b*2048+i][h]
  bf16* ao_ws   = (bf16*)(ws + 48 * MB);   // reuse qkv (dead after flash)
  bf16* out1_ws = (bf16*)(ws + 64 * MB);   // reuse qkv tail
  bf16* ff1_ws  = (bf16*)(ws + 80 * MB);   // 64 MiB [80,144): vT/rk/av dead after Wo
  bf16* core_ws = (bf16*)(ws + 48 * MB);   // reuse ao (dead after LN1)

  detect_kernel<<<dim3(1), dim3(256), 0, stream>>>((const unsigned*)d_in[0], flag);

  CvtTab tab;
  const int  srcidx[22] = {0,1,3,5,7,9,11,17,19, 4,6,8,10,12,13,14,15,16,18,20,21,22};
  bf16*      dsts[22]   = {wb_b,r_b,Wq_b,Wk_b,Wv_b,Wr_b,Wo_b,W1_b,W2_b,
                           bq_b,bk_b,bv_b,br_b,bo_b,rwb_b,rrb_b,g1_b,lb1_b,b1_b,b2_b,g2_b,lb2_b};
  const int  ns[22]     = {8388608,2097152,1048576,1048576,1048576,1048576,1048576,4194304,4194304,
                           1024,1024,1024,1024,1024,1024,1024,1024,1024,4096,1024,1024,1024};
  for (int s = 0; s < 22; ++s) { tab.src[s] = d_in[srcidx[s]]; tab.dst[s] = dsts[s]; tab.n[s] = ns[s]; }
  convert_kernel<<<dim3(512, 22), dim3(256), 0, stream>>>(tab, flag);

  const dim3 blk(256);

  // merged QKV projection: C[8192][3072] = wb @ [Wq;Wk;Wv]^T + [bq;bk;bv]
  gemm_bt_kernel<false><<<dim3(24, 64), blk, 0, stream>>>(wb_b, Wq_b, bq_b, qkv_ws, 8192, 3072, 1024);
  // V transpose to vT[h][bj]
  transpose_v_kernel<<<dim3(128, 16), blk, 0, stream>>>(qkv_ws, vT_ws);
  // rel-pos projection
  gemm_bt_kernel<false><<<dim3(8, 16), blk, 0, stream>>>(r_b, Wr_b, br_b, rk_ws, 2048, 1024, 1024);

  // flash attention: 1024 blocks of 512 threads (128 Q-rows each)
  flash_attn_kernel<<<dim3(1024), dim3(512), 0, stream>>>(qkv_ws, vT_ws, rk_ws, rwb_b, rrb_b, av_ws);

  // output projection + LN1
  gemm_bt_kernel<false><<<dim3(8, 64), blk, 0, stream>>>(av_ws, Wo_b, bo_b, ao_ws, 8192, 1024, 1024);
  ln_kernel<false><<<dim3(8192), blk, 0, stream>>>(wb_b, ao_ws, g1_b, lb1_b, out1_ws, nullptr, flag);

  // FFN (single-shot) + final LN (permutes rows back to [i][b], fp32 out)
  gemm_bt_kernel<true ><<<dim3(32, 64), blk, 0, stream>>>(out1_ws, W1_b, b1_b, ff1_ws, 8192, 4096, 1024);
  gemm_bt_kernel<false><<<dim3(8, 64), blk, 0, stream>>>(ff1_ws, W2_b, b2_b, core_ws, 8192, 1024, 4096);
  ln_kernel<true><<<dim3(8192), blk, 0, stream>>>(out1_ws, core_ws, g2_b, lb2_b, (bf16*)d_out, (float*)d_out, flag);
}